// Round 5
// baseline (195.958 us; speedup 1.0000x reference)
//
#include <hip/hip_runtime.h>
#include <math.h>

#define FEAT 4096
#define BATCH 4096
#define WPB 4                     // waves per block
#define NBLK (BATCH / WPB)        // 1024 blocks, one wave per row

// One WAVE per row; no __syncthreads, no LDS in the hot loop. Each wave
// streams its 3x16KB row (16 float4 per lane per array), shfl-reduces,
// lane 0 writes relu(2 - ||o1-o3|| + ||o1-o2||) to row_out[row].
__global__ __launch_bounds__(256) void row_dist_kernel(
    const float* __restrict__ o1, const float* __restrict__ o2,
    const float* __restrict__ o3, float* __restrict__ row_out)
{
    const int tid  = threadIdx.x;
    const int wave = tid >> 6;
    const int lane = tid & 63;
    const int row  = blockIdx.x * WPB + wave;

    const float4* p1 = (const float4*)(o1 + (size_t)row * FEAT);
    const float4* p2 = (const float4*)(o2 + (size_t)row * FEAT);
    const float4* p3 = (const float4*)(o3 + (size_t)row * FEAT);

    // 1024 float4/row over 64 lanes = 16 per lane; two independent
    // accumulator chains, two float4-triples in flight per iteration.
    float s13a = 0.f, s12a = 0.f, s13b = 0.f, s12b = 0.f;

    #pragma unroll
    for (int g = 0; g < 8; ++g) {
        const int i0 = lane + (2 * g + 0) * 64;
        const int i1 = lane + (2 * g + 1) * 64;
        const float4 a0 = p1[i0];
        const float4 c0 = p3[i0];
        const float4 b0 = p2[i0];
        const float4 a1 = p1[i1];
        const float4 c1 = p3[i1];
        const float4 b1 = p2[i1];
        float d;
        d = a0.x - c0.x; s13a += d * d;  d = a0.y - c0.y; s13a += d * d;
        d = a0.z - c0.z; s13a += d * d;  d = a0.w - c0.w; s13a += d * d;
        d = a0.x - b0.x; s12a += d * d;  d = a0.y - b0.y; s12a += d * d;
        d = a0.z - b0.z; s12a += d * d;  d = a0.w - b0.w; s12a += d * d;
        d = a1.x - c1.x; s13b += d * d;  d = a1.y - c1.y; s13b += d * d;
        d = a1.z - c1.z; s13b += d * d;  d = a1.w - c1.w; s13b += d * d;
        d = a1.x - b1.x; s12b += d * d;  d = a1.y - b1.y; s12b += d * d;
        d = a1.z - b1.z; s12b += d * d;  d = a1.w - b1.w; s12b += d * d;
    }

    float s13 = s13a + s13b;
    float s12 = s12a + s12b;

    // wave(64)-level butterfly reduce — no LDS, no barrier
    #pragma unroll
    for (int off = 32; off > 0; off >>= 1) {
        s13 += __shfl_down(s13, off, 64);
        s12 += __shfl_down(s12, off, 64);
    }

    if (lane == 0) {
        const float compare = 2.0f - sqrtf(s13) + sqrtf(s12);
        row_out[row] = fmaxf(compare, 0.0f);
    }
}

// Reduce the BATCH row values, scale by BATCH (broadcast-sum semantics).
__global__ __launch_bounds__(1024) void final_reduce_kernel(
    const float* __restrict__ row_vals, float* __restrict__ out)
{
    const int tid = threadIdx.x;
    float s = 0.0f;
    #pragma unroll
    for (int k = 0; k < BATCH / 1024; ++k) s += row_vals[tid + k * 1024];

    #pragma unroll
    for (int off = 32; off > 0; off >>= 1) s += __shfl_down(s, off, 64);

    __shared__ float ls[16];
    const int wave = tid >> 6;
    const int lane = tid & 63;
    if (lane == 0) ls[wave] = s;
    __syncthreads();
    if (tid == 0) {
        float t = 0.0f;
        #pragma unroll
        for (int i = 0; i < 16; ++i) t += ls[i];
        out[0] = t * (float)BATCH;
    }
}

extern "C" void kernel_launch(void* const* d_in, const int* in_sizes, int n_in,
                              void* d_out, int out_size, void* d_ws, size_t ws_size,
                              hipStream_t stream) {
    const float* o1 = (const float*)d_in[0];
    const float* o2 = (const float*)d_in[1];
    const float* o3 = (const float*)d_in[2];
    float* row_ws = (float*)d_ws;   // BATCH floats of scratch
    float* out = (float*)d_out;     // single fp32 scalar

    row_dist_kernel<<<NBLK, 256, 0, stream>>>(o1, o2, o3, row_ws);
    final_reduce_kernel<<<1, 1024, 0, stream>>>(row_ws, out);
}